// Round 3
// baseline (254.260 us; speedup 1.0000x reference)
//
#include <hip/hip_runtime.h>

// QuadraticBaseMorpho: out[h][w] = max_{dy,dx in [-3,3]} xpad[h+dy][w+dx] + nb[dy+3][dx+3]
// xpad = x padded with -10000. nb = -(se/se.max()) with center forced to -10000.
// se is even-symmetric -> the [::-1,::-1] flip is identity.
// Input (8,64,256,256) fp32 = 512 planes of 256x256.
//
// Round-3 experiment: NO LDS, NO BARRIERS. Rounds 0-2 (LDS ring + 2 barriers
// per sub-tile, lockstep waves) were all 94-96 us clock-normalized despite
// halving VALU issues and raising occupancy -> the wall is the serialized
// ds_read->compute->barrier schedule, not any single pipe. Here each wave
// processes independent 4-row chunks; each input row is read directly from
// global as 3 overlapping aligned vf4 loads (L1 serves the 7x vertical and
// 2.5x chunk-halo reuse; window per block = 22 rows = 22 KB < 32 KB L1).
// Edge lanes (0, 63) clamp their halo load address into the row and fix the
// out-of-range taps with pre-masked selects. Virtual pad rows (r<0, r>=256)
// are skipped entirely: a -MAXV+w candidate (~-10000) can never beat a real
// candidate (x+w >= ~-7), and dy=0 always supplies real taps -> bit-identical.
//
// Inner loop unchanged: per (t,c) 3 v_pk_add_f32 + 1 add + 3 v_max3 + 1 max.
// VGPR ~60 -> __launch_bounds__(256,8): 8 blocks/CU, one residency round,
// fully independent waves.

#define MAXV 10000.0f

constexpr int H = 256;
constexpr int W = 256;

typedef float vf4 __attribute__((ext_vector_type(4)));
typedef float vf2 __attribute__((ext_vector_type(2)));

__global__ __launch_bounds__(256, 8) void morpho_kernel(
    const float* __restrict__ x,
    const float* __restrict__ k1p,
    const float* __restrict__ k2p,
    const float* __restrict__ k3p,
    float* __restrict__ out) {
  const int tid = threadIdx.x;
  const int lane = tid & 63;
  const int wid = __builtin_amdgcn_readfirstlane(tid >> 6);  // wave id, uniform
  const int p = blockIdx.x >> 2;                 // plane (512)
  const int ty0 = (blockIdx.x & 3) * 64;         // block's first output row

  const float* __restrict__ xp = x + (size_t)p * (H * W);
  float* __restrict__ op = out + (size_t)p * (H * W);

  // ---- SE: one weight per lane (8x8 grid), shuffle-max, readlane -> SGPRs ----
  const float k1v = k1p[0], k2v = k2p[0], k3v = k3p[0];
  const int ia = lane >> 3, ib = lane & 7;
  const float xg = (float)(((ib < 6) ? ib : 6) - 3);   // clamp dup lanes; max unaffected
  const float yg = (float)(((ia < 6) ? ia : 6) - 3);
  const float sev = k1v * (xg * xg) + 2.0f * k2v * (xg * yg) + k3v * (yg * yg);
  float mx = sev;
#pragma unroll
  for (int off = 32; off; off >>= 1) mx = fmaxf(mx, __shfl_xor(mx, off, 64));
  const float wv = 0.0f - sev * (1.0f / mx);

  // weight row d: pairs (w0,w1)(w2,w3)(w4,w5) + scalar w6 -> 49 SGPRs total
  vf2 wp[7][3];
  float w6[7];
#pragma unroll
  for (int d = 0; d < 7; ++d) {
#pragma unroll
    for (int m = 0; m < 3; ++m) {
      vf2 pr;
      pr.x = __int_as_float(__builtin_amdgcn_readlane(__float_as_int(wv), d * 8 + 2 * m));
      pr.y = __int_as_float(__builtin_amdgcn_readlane(__float_as_int(wv), d * 8 + 2 * m + 1));
      wp[d][m] = pr;
    }
    w6[d] = __int_as_float(__builtin_amdgcn_readlane(__float_as_int(wv), d * 8 + 6));
  }
  wp[3][1].y = -MAXV;                            // masked center (d=3, j=3)

  // ---- per-lane load offsets (float indices), clamped into the row ----
  const bool l0 = (lane == 0);
  const bool l63 = (lane == 63);
  const int o1 = lane * 4;                       // q1: cols lane*4 .. +3
  const int o0 = l0 ? o1 : o1 - 4;               // q0: cols lane*4-4 .. -1
  const int o2 = l63 ? o1 : o1 + 4;              // q2: cols lane*4+4 .. +7

  // ---- 4 chunks of 4 output rows per wave, interleaved across waves ----
  for (int k = 0; k < 4; ++k) {
    const int y0c = ty0 + 4 * wid + 16 * k;      // chunk base output row

    float acc[4][4];
#pragma unroll
    for (int t = 0; t < 4; ++t)
#pragma unroll
      for (int c = 0; c < 4; ++c) acc[t][c] = -INFINITY;

#pragma unroll
    for (int iy = 0; iy < 10; ++iy) {            // input rows y0c-3 .. y0c+6
      const int r = y0c - 3 + iy;
      if (r < 0 || r >= H) continue;             // wave-uniform scalar branch
      const float* __restrict__ rb = xp + r * W;

      vf4 q0 = *reinterpret_cast<const vf4*>(rb + o0);  // buf[0..3]
      vf4 q1 = *reinterpret_cast<const vf4*>(rb + o1);  // buf[4..7]
      vf4 q2 = *reinterpret_cast<const vf4*>(rb + o2);  // buf[8..11]

      // edge fixes: lane 0's cols -3..-1, lane 63's cols 256..258 -> -MAXV
      q0.y = l0 ? -MAXV : q0.y;
      q0.z = l0 ? -MAXV : q0.z;
      q0.w = l0 ? -MAXV : q0.w;
      q2.x = l63 ? -MAXV : q2.x;
      q2.y = l63 ? -MAXV : q2.y;
      q2.z = l63 ? -MAXV : q2.z;

      // odd-start pairs (2 movs each): (b1,b2)(b3,b4)(b5,b6)(b7,b8)
      const vf2 O0 = __builtin_shufflevector(q0, q0, 1, 2);
      const vf2 O1 = __builtin_shufflevector(q0, q1, 3, 4);
      const vf2 O2 = __builtin_shufflevector(q1, q1, 1, 2);
      const vf2 O3 = __builtin_shufflevector(q1, q2, 3, 4);
      // even-start pairs (free quad sub-pairs): (b2,b3)(b4,b5)(b6,b7)(b8,b9)
      const vf2 E0 = __builtin_shufflevector(q0, q0, 2, 3);
      const vf2 E1 = __builtin_shufflevector(q1, q1, 0, 1);
      const vf2 E2 = __builtin_shufflevector(q1, q1, 2, 3);
      const vf2 E3 = __builtin_shufflevector(q2, q2, 0, 1);

      const vf2 P[4][3] = {{O0, O1, O2}, {E0, E1, E2}, {O1, O2, O3}, {E1, E2, E3}};
      const float T[4] = {q1.w, q2.x, q2.y, q2.z};

#pragma unroll
      for (int t = 0; t < 4; ++t) {
        const int dyr = iy - t;                  // nb row index = dy+3
        if (dyr < 0 || dyr > 6) continue;        // dead after unroll
#pragma unroll
        for (int c = 0; c < 4; ++c) {
          const vf2 a = P[c][0] + wp[dyr][0];    // v_pk_add_f32
          const vf2 b = P[c][1] + wp[dyr][1];    // v_pk_add_f32
          const vf2 g = P[c][2] + wp[dyr][2];    // v_pk_add_f32
          const float s6 = T[c] + w6[dyr];
          const float m0 = fmaxf(fmaxf(a.x, a.y), b.x);   // v_max3
          const float m1 = fmaxf(fmaxf(b.y, g.x), g.y);   // v_max3
          const float m2 = fmaxf(fmaxf(s6, m0), m1);      // v_max3
          acc[t][c] = fmaxf(acc[t][c], m2);
        }
      }
    }

    // store chunk (nontemporal: output is never re-read; keep L1/L2 for x)
#pragma unroll
    for (int t = 0; t < 4; ++t) {
      vf4 v;
      v.x = acc[t][0];
      v.y = acc[t][1];
      v.z = acc[t][2];
      v.w = acc[t][3];
      __builtin_nontemporal_store(
          v, reinterpret_cast<vf4*>(&op[(y0c + t) * W + lane * 4]));
    }
  }
}

extern "C" void kernel_launch(void* const* d_in, const int* in_sizes, int n_in,
                              void* d_out, int out_size, void* d_ws, size_t ws_size,
                              hipStream_t stream) {
  const float* x = (const float*)d_in[0];
  const float* k1 = (const float*)d_in[1];
  const float* k2 = (const float*)d_in[2];
  const float* k3 = (const float*)d_in[3];
  float* outp = (float*)d_out;

  const int planes = 8 * 64;                     // 512
  const int blocks = planes * 4;                 // 2048 (64 rows per block)
  morpho_kernel<<<dim3(blocks), dim3(256), 0, stream>>>(x, k1, k2, k3, outp);
}